// Round 1
// baseline (1348.614 us; speedup 1.0000x reference)
//
#include <hip/hip_runtime.h>
#include <hip/hip_bf16.h>
#include <math.h>

#define N 4096
#define IN_FT 512
#define OUT_FT 512
#define COS_THR 0.5f
#define COS_K 10
#define EPSN 1e-12f

#define BM 64
#define BN 64
#define BK 16

// ---------- row-normalize x ----------
__global__ __launch_bounds__(256) void rownorm_k(const float* __restrict__ x,
                                                 float* __restrict__ xn) {
    int row = blockIdx.x;
    const float* xr = x + (size_t)row * IN_FT;
    float s = 0.f;
    for (int j = threadIdx.x; j < IN_FT; j += 256) { float v = xr[j]; s += v * v; }
    __shared__ float red[256];
    red[threadIdx.x] = s; __syncthreads();
    for (int off = 128; off > 0; off >>= 1) {
        if (threadIdx.x < off) red[threadIdx.x] += red[threadIdx.x + off];
        __syncthreads();
    }
    float inv = 1.0f / fmaxf(sqrtf(red[0]), 1e-12f);
    for (int j = threadIdx.x; j < IN_FT; j += 256)
        xn[(size_t)row * IN_FT + j] = xr[j] * inv;
}

// ---------- C[M,N] = A[M,K] @ B[N,K]^T (+bias), f32 ----------
__global__ __launch_bounds__(256) void matmul_abt_k(const float* __restrict__ A,
                                                    const float* __restrict__ B,
                                                    const float* __restrict__ bias,
                                                    float* __restrict__ C,
                                                    int K, int lda, int ldb, int ldc) {
    __shared__ float As[BK][BM + 1];
    __shared__ float Bs[BK][BN + 1];
    int i0 = blockIdx.y * BM, j0 = blockIdx.x * BN;
    int tid = threadIdx.x;
    int tx = tid & 15, ty = tid >> 4;
    float acc[4][4] = {{0.f}};
    for (int k0 = 0; k0 < K; k0 += BK) {
#pragma unroll
        for (int l = 0; l < 4; ++l) {
            int idx = tid + l * 256;
            int m = idx >> 4, k = idx & 15;
            As[k][m] = A[(size_t)(i0 + m) * lda + k0 + k];
        }
#pragma unroll
        for (int l = 0; l < 4; ++l) {
            int idx = tid + l * 256;
            int n = idx >> 4, k = idx & 15;
            Bs[k][n] = B[(size_t)(j0 + n) * ldb + k0 + k];
        }
        __syncthreads();
#pragma unroll
        for (int k = 0; k < BK; ++k) {
            float a[4], b[4];
#pragma unroll
            for (int i = 0; i < 4; ++i) a[i] = As[k][ty * 4 + i];
#pragma unroll
            for (int j = 0; j < 4; ++j) b[j] = Bs[k][tx * 4 + j];
#pragma unroll
            for (int i = 0; i < 4; ++i)
#pragma unroll
                for (int j = 0; j < 4; ++j) acc[i][j] += a[i] * b[j];
        }
        __syncthreads();
    }
#pragma unroll
    for (int i = 0; i < 4; ++i) {
        int r = i0 + ty * 4 + i;
#pragma unroll
        for (int j = 0; j < 4; ++j) {
            int c = j0 + tx * 4 + j;
            float v = acc[i][j];
            if (bias) v += bias[c];
            C[(size_t)r * ldc + c] = v;
        }
    }
}

// ---------- per-row top-k + threshold mask; Hm written in-place over cos ----------
__global__ __launch_bounds__(256) void topk_mask_k(float* __restrict__ cosHm,
                                                   const float* __restrict__ Hmat) {
    int row = blockIdx.x;
    __shared__ float vals[N];
    __shared__ unsigned char flag[N];
    __shared__ float rv[256];
    __shared__ int ri[256];
    float* crow = cosHm + (size_t)row * N;
    for (int j = threadIdx.x; j < N; j += 256) {
        float v = crow[j];
        vals[j] = v;
        flag[j] = (v > COS_THR) ? 1 : 0;
    }
    __syncthreads();
    for (int t = 0; t < COS_K; ++t) {
        float best = -INFINITY;
        int bidx = 0x7fffffff;
        for (int j = threadIdx.x; j < N; j += 256) {
            float v = vals[j];
            if (v > best) { best = v; bidx = j; }  // ascending j -> lowest idx on tie
        }
        rv[threadIdx.x] = best; ri[threadIdx.x] = bidx;
        __syncthreads();
        for (int off = 128; off > 0; off >>= 1) {
            if (threadIdx.x < off) {
                float v2 = rv[threadIdx.x + off]; int i2 = ri[threadIdx.x + off];
                float v1 = rv[threadIdx.x];       int i1 = ri[threadIdx.x];
                if (v2 > v1 || (v2 == v1 && i2 < i1)) { rv[threadIdx.x] = v2; ri[threadIdx.x] = i2; }
            }
            __syncthreads();
        }
        int w = ri[0];
        if (threadIdx.x == 0) { vals[w] = -INFINITY; flag[w] = 1; }
        __syncthreads();
    }
    const float* hrow = Hmat + (size_t)row * N;
    for (int j = threadIdx.x; j < N; j += 256)
        crow[j] = flag[j] ? hrow[j] : 0.0f;
}

// ---------- column L1 sums of (w1 .* Hm), two-stage deterministic ----------
__global__ __launch_bounds__(256) void colsum_part_k(const float* __restrict__ w,
                                                     const float* __restrict__ Hm,
                                                     float* __restrict__ part) {
    int c = blockIdx.x * 256 + threadIdx.x;
    int r0 = blockIdx.y * 64;
    float s = 0.f;
    for (int r = r0; r < r0 + 64; ++r) {
        size_t off = (size_t)r * N + c;
        s += fabsf(w[off] * Hm[off]);
    }
    part[(size_t)blockIdx.y * N + c] = s;
}

__global__ __launch_bounds__(256) void colsum_reduce_k(const float* __restrict__ part,
                                                       float* __restrict__ out) {
    int c = blockIdx.x * 256 + threadIdx.x;
    float s = 0.f;
    for (int b = 0; b < 64; ++b) s += part[(size_t)b * N + c];
    out[c] = s;
}

// ---------- row L1 sums of (w2 .* Hm) ----------
__global__ __launch_bounds__(256) void rowsum_k(const float* __restrict__ w,
                                                const float* __restrict__ Hm,
                                                float* __restrict__ out) {
    int row = blockIdx.x;
    float s = 0.f;
    for (int j = threadIdx.x; j < N; j += 256) {
        size_t off = (size_t)row * N + j;
        s += fabsf(w[off] * Hm[off]);
    }
    __shared__ float red[256];
    red[threadIdx.x] = s; __syncthreads();
    for (int off = 128; off > 0; off >>= 1) {
        if (threadIdx.x < off) red[threadIdx.x] += red[threadIdx.x + off];
        __syncthreads();
    }
    if (threadIdx.x == 0) out[row] = red[0];
}

// ---------- h2[e,f] = (sum_v w1[v,e]*Hm[v,e]*h[v,f]) / max(csum[e],eps) ----------
__global__ __launch_bounds__(256) void agg1_k(const float* __restrict__ w1,
                                              const float* __restrict__ Hm,
                                              const float* __restrict__ h,
                                              const float* __restrict__ csum,
                                              float* __restrict__ h2) {
    __shared__ float As[BK][BM + 1];
    __shared__ float Bs[BK][BN + 1];
    int e0 = blockIdx.y * BM, f0 = blockIdx.x * BN;
    int tid = threadIdx.x;
    int tx = tid & 15, ty = tid >> 4;
    float acc[4][4] = {{0.f}};
    for (int v0 = 0; v0 < N; v0 += BK) {
#pragma unroll
        for (int l = 0; l < 4; ++l) {
            int idx = tid + l * 256;
            int k = idx >> 6, m = idx & 63;
            size_t off = (size_t)(v0 + k) * N + e0 + m;
            As[k][m] = w1[off] * Hm[off];
        }
#pragma unroll
        for (int l = 0; l < 4; ++l) {
            int idx = tid + l * 256;
            int k = idx >> 6, n = idx & 63;
            Bs[k][n] = h[(size_t)(v0 + k) * OUT_FT + f0 + n];
        }
        __syncthreads();
#pragma unroll
        for (int k = 0; k < BK; ++k) {
            float a[4], b[4];
#pragma unroll
            for (int i = 0; i < 4; ++i) a[i] = As[k][ty * 4 + i];
#pragma unroll
            for (int j = 0; j < 4; ++j) b[j] = Bs[k][tx * 4 + j];
#pragma unroll
            for (int i = 0; i < 4; ++i)
#pragma unroll
                for (int j = 0; j < 4; ++j) acc[i][j] += a[i] * b[j];
        }
        __syncthreads();
    }
#pragma unroll
    for (int i = 0; i < 4; ++i) {
        int e = e0 + ty * 4 + i;
        float sc = 1.0f / fmaxf(csum[e], EPSN);
#pragma unroll
        for (int j = 0; j < 4; ++j) {
            int f = f0 + tx * 4 + j;
            h2[(size_t)e * OUT_FT + f] = acc[i][j] * sc;
        }
    }
}

// ---------- out[v,f] = (sum_e w2[v,e]*Hm[v,e]*h2[e,f]) / max(rsum[v],eps) ----------
__global__ __launch_bounds__(256) void agg2_k(const float* __restrict__ w2,
                                              const float* __restrict__ Hm,
                                              const float* __restrict__ h2,
                                              const float* __restrict__ rsum,
                                              float* __restrict__ out) {
    __shared__ float As[BK][BM + 1];
    __shared__ float Bs[BK][BN + 1];
    int r0 = blockIdx.y * BM, f0 = blockIdx.x * BN;
    int tid = threadIdx.x;
    int tx = tid & 15, ty = tid >> 4;
    float acc[4][4] = {{0.f}};
    for (int k0 = 0; k0 < N; k0 += BK) {
#pragma unroll
        for (int l = 0; l < 4; ++l) {
            int idx = tid + l * 256;
            int m = idx >> 4, k = idx & 15;
            size_t off = (size_t)(r0 + m) * N + k0 + k;
            As[k][m] = w2[off] * Hm[off];
        }
#pragma unroll
        for (int l = 0; l < 4; ++l) {
            int idx = tid + l * 256;
            int k = idx >> 6, n = idx & 63;
            Bs[k][n] = h2[(size_t)(k0 + k) * OUT_FT + f0 + n];
        }
        __syncthreads();
#pragma unroll
        for (int k = 0; k < BK; ++k) {
            float a[4], b[4];
#pragma unroll
            for (int i = 0; i < 4; ++i) a[i] = As[k][ty * 4 + i];
#pragma unroll
            for (int j = 0; j < 4; ++j) b[j] = Bs[k][tx * 4 + j];
#pragma unroll
            for (int i = 0; i < 4; ++i)
#pragma unroll
                for (int j = 0; j < 4; ++j) acc[i][j] += a[i] * b[j];
        }
        __syncthreads();
    }
#pragma unroll
    for (int i = 0; i < 4; ++i) {
        int r = r0 + ty * 4 + i;
        float sc = 1.0f / fmaxf(rsum[r], EPSN);
#pragma unroll
        for (int j = 0; j < 4; ++j) {
            int f = f0 + tx * 4 + j;
            out[(size_t)r * OUT_FT + f] = acc[i][j] * sc;
        }
    }
}

extern "C" void kernel_launch(void* const* d_in, const int* in_sizes, int n_in,
                              void* d_out, int out_size, void* d_ws, size_t ws_size,
                              hipStream_t stream) {
    const float* x      = (const float*)d_in[0];   // [4096,512]
    const float* Hmat   = (const float*)d_in[1];   // [4096,4096]
    const float* proj_w = (const float*)d_in[2];   // [512,512]
    const float* proj_b = (const float*)d_in[3];   // [512]
    const float* w1     = (const float*)d_in[4];   // [4096,4096]
    const float* w2     = (const float*)d_in[5];   // [4096,4096]
    float* out = (float*)d_out;

    char* ws = (char*)d_ws;
    float* xn    = (float*)(ws + 0);          //  8 MB [4096,512]
    float* cosHm = (float*)(ws + 8388608);    // 64 MB [4096,4096] cos -> Hm in place
    float* h     = (float*)(ws + 75497472);   //  8 MB [4096,512]
    float* h2    = (float*)(ws + 83886080);   //  8 MB [4096,512]
    float* cs1   = (float*)(ws + 92274688);   // 16 KB [4096]
    float* rs2   = (float*)(ws + 92291072);   // 16 KB [4096]
    float* part  = (float*)(ws + 92307456);   //  1 MB [64,4096]

    // 1. xn = x / max(||x||, eps)
    rownorm_k<<<N, 256, 0, stream>>>(x, xn);
    // 2. cos = xn @ xn^T   (f32 — precision critical for top-k selection)
    matmul_abt_k<<<dim3(N / BN, N / BM), 256, 0, stream>>>(xn, xn, nullptr, cosHm,
                                                           IN_FT, IN_FT, IN_FT, N);
    // 3. mask = (cos > thr) | topk ; Hm = H * mask  (in place over cos)
    topk_mask_k<<<N, 256, 0, stream>>>(cosHm, Hmat);
    // 4. h = x @ proj_w^T + proj_b
    matmul_abt_k<<<dim3(OUT_FT / BN, N / BM), 256, 0, stream>>>(x, proj_w, proj_b, h,
                                                                IN_FT, IN_FT, IN_FT, OUT_FT);
    // 5. L1 sums
    colsum_part_k<<<dim3(16, 64), 256, 0, stream>>>(w1, cosHm, part);
    colsum_reduce_k<<<16, 256, 0, stream>>>(part, cs1);
    rowsum_k<<<N, 256, 0, stream>>>(w2, cosHm, rs2);
    // 6. h2 = normalize((w1.*Hm)^T) @ h
    agg1_k<<<dim3(OUT_FT / BN, N / BM), 256, 0, stream>>>(w1, cosHm, h, cs1, h2);
    // 7. out = normalize(w2.*Hm) @ h2
    agg2_k<<<dim3(OUT_FT / BN, N / BM), 256, 0, stream>>>(w2, cosHm, h2, rs2, out);
}